// Round 4
// baseline (329.319 us; speedup 1.0000x reference)
//
#include <hip/hip_runtime.h>
#include <stdint.h>

// BSpline KAN layer: out[b,o] = sum_{i,k} bases(tanh(x[b,i]))[k] * C[i,o,k]
// == GEMM M=8192, N=512, K=4096 with generated A. bf16 MFMA path.
// R2: 64x128 tile, LDS double buffer, 84 us (MfmaUtil 16, VALUBusy 37, occ 20).
// R3 (8 waves, launch_bounds(512,4)) REGRESSED to 131 us: VGPR squeezed to 32,
//   B-loads serialized against use, barrier-locked iteration got LONGER.
// R4: key insight — the mfma_16x16x32_bf16 A-fragment (lane = row lane16,
//   k = quad*8+j contiguous) is EXACTLY one bspline_pack() output
//   (i = it*8 + ks*4 + quad). So generate A fragments directly in registers:
//   NO LDS, NO barriers, NO ds_read. Wave owns 16 rows x 128 cols; B frags
//   register-double-buffered from L2 (4 waves/block share cols -> L1 hits).
// R5/R6: resubmits — R4/R5 benches were infra failures (container acquire),
//   no counters returned. Kernel re-audited both times: no OOB (BtT max
//   offset = 4 MB exactly), no data-dependent loops, ~185 VGPR no-spill,
//   harness-rule-clean. Theory still untested.

typedef short s16x8 __attribute__((ext_vector_type(8)));   // 8 bf16
typedef float f32x4 __attribute__((ext_vector_type(4)));

#define BATCH 8192
#define IN_F  512
#define OUT_F 512
#define NB    8            // GRID_SIZE + SPLINE_ORDER
#define KKTOT (IN_F * NB)  // 4096
#define NITER (IN_F / NB)  // 64 K-tiles of 64

__device__ __forceinline__ uint32_t f2bf(float f) {
    union { float f; uint32_t u; } v; v.f = f;
    return (v.u + 0x7FFFu + ((v.u >> 16) & 1u)) >> 16;   // RNE bf16
}

__device__ __forceinline__ s16x8 u4_to_s8(uint4 v) {
    union { uint4 u; s16x8 s; } c; c.u = v; return c.s;
}

// 8 basis values for one x, packed bf16 into 16 bytes (4 nonzero cubic
// B-spline weights shifted to slot j-3; uniform grid h=0.4, g0=-2.2).
__device__ __forceinline__ uint4 bspline_pack(float xraw) {
    float e  = __expf(2.0f * xraw);
    float xn = 1.0f - 2.0f / (e + 1.0f);          // tanh; inf->1, 0->-1
    float u  = __fmaf_rn(xn, 2.5f, 5.5f);         // (xn + 2.2) / 0.4
    float fj = floorf(u);
    fj = fminf(fmaxf(fj, 3.0f), 7.0f);            // cell j in [3,7]
    float t  = u - fj;                            // local coord in [0,1]
    float omt = 1.0f - t;
    float t2 = t * t;
    float t3 = t2 * t;
    const float s = 0.16666666666666666f;
    float w0 = s * omt * omt * omt;
    float w3 = s * t3;
    float w1 = s * __fmaf_rn(3.0f, t3, __fmaf_rn(-6.0f, t2, 4.0f));
    float w2 = 1.0f - w0 - w1 - w3;               // partition of unity
    uint64_t packed = (uint64_t)(f2bf(w0) | (f2bf(w1) << 16))
                    | ((uint64_t)(f2bf(w2) | (f2bf(w3) << 16)) << 32);
    int sh = ((int)fj - 3) * 16;                  // 0,16,32,48,64 bits
    uint64_t lo, hi;
    if (sh == 0)      { lo = packed;       hi = 0ull; }
    else if (sh < 64) { lo = packed << sh; hi = packed >> (64 - sh); }
    else              { lo = 0ull;         hi = packed; }
    return make_uint4((uint32_t)lo, (uint32_t)(lo >> 32),
                      (uint32_t)hi, (uint32_t)(hi >> 32));
}

// C[i][o][k] fp32 -> BtT[o][i*8+k] bf16. o-fastest: coalesced reads,
// scattered 16B stores (fire-and-forget, write-combined).
__global__ __launch_bounds__(256)
void prep_bt(const float* __restrict__ C, unsigned short* __restrict__ BtT) {
    int t = blockIdx.x * 256 + threadIdx.x;
    int o = t & (OUT_F - 1);
    int i = t >> 9;
    const float4* src = (const float4*)(C + ((size_t)i * OUT_F + o) * NB);
    float4 c0 = src[0];
    float4 c1 = src[1];
    uint4 val;
    val.x = f2bf(c0.x) | (f2bf(c0.y) << 16);
    val.y = f2bf(c0.z) | (f2bf(c0.w) << 16);
    val.z = f2bf(c1.x) | (f2bf(c1.y) << 16);
    val.w = f2bf(c1.z) | (f2bf(c1.w) << 16);
    *(uint4*)(BtT + (size_t)o * KKTOT + (size_t)i * NB) = val;
}

// Barrier-free GEMM: each wave owns 16 rows x 128 cols. A fragments are
// bspline_pack outputs computed per-lane per-iter; B fragments register
// double-buffered (bA/bB, named arrays -> no scratch per rule #20).
__global__ __launch_bounds__(256, 2)
void kan_gemm(const float* __restrict__ X, const unsigned short* __restrict__ BtT,
              float* __restrict__ Out) {
    const int tid    = threadIdx.x;
    const int lane   = tid & 63;
    const int wv     = tid >> 6;     // 0..3: 16-row slice within block
    const int lane16 = lane & 15;
    const int quad   = lane >> 4;

    const int rowA = blockIdx.y * 64 + wv * 16 + lane16;  // this lane's A row
    const int col0 = blockIdx.x * 128;

    const float* xrow = X + (size_t)rowA * IN_F;
    // B frag base: col = col0 + cn*16 + lane16, k = it*64 + ks*32 + quad*8
    const unsigned short* bb = BtT + (size_t)(col0 + lane16) * KKTOT + quad * 8;

    f32x4 acc[8] = {};
    s16x8 bA[16], bB[16];            // [cn*2 + ks]

    // prologue: B for iter 0, x for iter 0
    #pragma unroll
    for (int cn = 0; cn < 8; ++cn) {
        bA[cn * 2 + 0] = *(const s16x8*)(bb + (size_t)cn * 16 * KKTOT);
        bA[cn * 2 + 1] = *(const s16x8*)(bb + (size_t)cn * 16 * KKTOT + 32);
    }
    float xc0 = xrow[quad];
    float xc1 = xrow[4 + quad];
    float xn0 = 0.0f, xn1 = 0.0f;

#define KAN_BODY(CUR, NXT, IT)                                                   \
    {                                                                            \
        if ((IT) + 1 < NITER) {                                                  \
            const int kn = ((IT) + 1) * 64;                                      \
            _Pragma("unroll")                                                    \
            for (int cn = 0; cn < 8; ++cn) {                                     \
                NXT[cn * 2 + 0] = *(const s16x8*)(bb + (size_t)cn * 16 * KKTOT + kn);      \
                NXT[cn * 2 + 1] = *(const s16x8*)(bb + (size_t)cn * 16 * KKTOT + kn + 32); \
            }                                                                    \
            xn0 = xrow[((IT) + 1) * 8 + quad];                                   \
            xn1 = xrow[((IT) + 1) * 8 + 4 + quad];                               \
        }                                                                        \
        uint4 p0 = bspline_pack(xc0);                                            \
        uint4 p1 = bspline_pack(xc1);                                            \
        s16x8 af0 = u4_to_s8(p0);                                                \
        s16x8 af1 = u4_to_s8(p1);                                                \
        _Pragma("unroll")                                                        \
        for (int cn = 0; cn < 8; ++cn)                                           \
            acc[cn] = __builtin_amdgcn_mfma_f32_16x16x32_bf16(                   \
                af0, CUR[cn * 2 + 0], acc[cn], 0, 0, 0);                         \
        _Pragma("unroll")                                                        \
        for (int cn = 0; cn < 8; ++cn)                                           \
            acc[cn] = __builtin_amdgcn_mfma_f32_16x16x32_bf16(                   \
                af1, CUR[cn * 2 + 1], acc[cn], 0, 0, 0);                         \
        xc0 = xn0; xc1 = xn1;                                                    \
    }

    for (int it = 0; it < NITER; it += 2) {
        KAN_BODY(bA, bB, it);
        KAN_BODY(bB, bA, it + 1);
    }
#undef KAN_BODY

    // Epilogue: C/D layout col=lane&15, row=quad*4+reg
    const int orow = blockIdx.y * 64 + wv * 16 + quad * 4;
    #pragma unroll
    for (int cn = 0; cn < 8; ++cn) {
        float* dst = Out + (size_t)orow * OUT_F + col0 + cn * 16 + lane16;
        #pragma unroll
        for (int r = 0; r < 4; ++r)
            dst[(size_t)r * OUT_F] = acc[cn][r];
    }
}

extern "C" void kernel_launch(void* const* d_in, const int* in_sizes, int n_in,
                              void* d_out, int out_size, void* d_ws, size_t ws_size,
                              hipStream_t stream) {
    const float* X  = (const float*)d_in[0];   // (8192, 512) f32
    const float* C  = (const float*)d_in[1];   // (512, 512, 8) f32
    // d_in[2] = grid (uniform; constants hardcoded)
    float* Out = (float*)d_out;                // (8192, 512) f32
    unsigned short* BtT = (unsigned short*)d_ws;  // 4 MB bf16 [o][i*8+k]

    prep_bt<<<dim3((IN_F * OUT_F) / 256), 256, 0, stream>>>(C, BtT);
    kan_gemm<<<dim3(OUT_F / 128, BATCH / 64), 256, 0, stream>>>(X, BtT, Out);
}

// Round 5
// 196.949 us; speedup vs baseline: 1.6721x; 1.6721x over previous
//
#include <hip/hip_runtime.h>
#include <hip/hip_bf16.h>
#include <stdint.h>

// BSpline KAN layer: out[b,o] = sum_{i,k} bases(tanh(x[b,i]))[k] * C[i,o,k]
// == GEMM M=8192, N=512, K=4096 with generated A. bf16 MFMA path.
// R2: A-in-LDS dbuf, B-from-global, 64x128, 4 waves: 84 us
//     (MfmaUtil 16, VALUBusy 37, occ 20.6 — latency-bound, grid 2 blocks/CU).
// R3: 8-wave variant REGRESSED (VGPR squeezed to 32, loads serialized).
// R4: barrier-free all-reg variant REGRESSED to 268 us: VGPR_Count=92 proves
//     the compiler SANK the B-prefetch loads (occupancy-targeting scheduler),
//     exposing L2 latency per iter; plus per-wave full-width B = 2 GB through
//     the per-CU TA port (~2048 lines/CU-iter vs 620 cyc MFMA). Dead end.
// R7: back to R2 skeleton, three fixes from the R4 diagnosis:
//     (1) BM 32 -> grid 1024 = 4 blocks/CU (16 waves/CU): independent
//         barriers overlap across blocks; was grid-limited at 2.
//     (2) B prefetched ONE iter ahead into 4 frags (16 VGPR — too small to
//         trigger sinking) pinned by sched_barrier(0) right after issue.
//     (3) pack uses __float2bfloat16 scalar casts (compiler fuses to
//         v_cvt_pk_bf16_f32, per m240) instead of 4x manual bit-RNE.

typedef short s16x8 __attribute__((ext_vector_type(8)));   // 8 bf16
typedef float f32x4 __attribute__((ext_vector_type(4)));

#define BATCH 8192
#define IN_F  512
#define OUT_F 512
#define NB    8            // GRID_SIZE + SPLINE_ORDER
#define KKTOT (IN_F * NB)  // 4096
#define BM 32
#define BN 128
#define BK 64              // 8 i's per K-tile
#define LDK 72             // padded row (ushorts): 144 B -> 2-way-max bank aliasing
#define NITER (IN_F / NB)  // 64

__device__ __forceinline__ uint32_t f2bf(float f) {
    union { float f; uint32_t u; } v; v.f = f;
    return (v.u + 0x7FFFu + ((v.u >> 16) & 1u)) >> 16;   // RNE bf16
}

__device__ __forceinline__ uint32_t bf16bits(float a) {
    __hip_bfloat16 h = __float2bfloat16(a);               // RNE; compiler pairs
    union { __hip_bfloat16 h; unsigned short u; } c; c.h = h;
    return (uint32_t)c.u;
}

// 8 basis values for one x, packed bf16 into 16 bytes (4 nonzero cubic
// B-spline weights shifted to slot j-3; uniform grid h=0.4, g0=-2.2).
__device__ __forceinline__ uint4 bspline_pack(float xraw) {
    float e  = __expf(2.0f * xraw);
    float xn = 1.0f - 2.0f / (e + 1.0f);          // tanh; inf->1, 0->-1
    float u  = __fmaf_rn(xn, 2.5f, 5.5f);         // (xn + 2.2) / 0.4
    float fj = floorf(u);
    fj = fminf(fmaxf(fj, 3.0f), 7.0f);            // cell j in [3,7]
    float t  = u - fj;                            // local coord in [0,1]
    float omt = 1.0f - t;
    float t2 = t * t;
    float t3 = t2 * t;
    const float s = 0.16666666666666666f;
    float w0 = s * omt * omt * omt;
    float w3 = s * t3;
    float w1 = s * __fmaf_rn(3.0f, t3, __fmaf_rn(-6.0f, t2, 4.0f));
    float w2 = 1.0f - w0 - w1 - w3;               // partition of unity
    uint64_t packed = (uint64_t)(bf16bits(w0) | (bf16bits(w1) << 16))
                    | ((uint64_t)(bf16bits(w2) | (bf16bits(w3) << 16)) << 32);
    int sh = ((int)fj - 3) * 16;                  // 0,16,32,48,64 bits
    uint64_t lo, hi;
    if (sh == 0)      { lo = packed;       hi = 0ull; }
    else if (sh < 64) { lo = packed << sh; hi = packed >> (64 - sh); }
    else              { lo = 0ull;         hi = packed; }
    return make_uint4((uint32_t)lo, (uint32_t)(lo >> 32),
                      (uint32_t)hi, (uint32_t)(hi >> 32));
}

// C[i][o][k] fp32 -> BtT[o][i*8+k] bf16. o-fastest: coalesced reads,
// scattered 16B stores (fire-and-forget, write-combined). Verified in R0-R2.
__global__ __launch_bounds__(256)
void prep_bt(const float* __restrict__ C, unsigned short* __restrict__ BtT) {
    int t = blockIdx.x * 256 + threadIdx.x;
    int o = t & (OUT_F - 1);
    int i = t >> 9;
    const float4* src = (const float4*)(C + ((size_t)i * OUT_F + o) * NB);
    float4 c0 = src[0];
    float4 c1 = src[1];
    uint4 val;
    val.x = f2bf(c0.x) | (f2bf(c0.y) << 16);
    val.y = f2bf(c0.z) | (f2bf(c0.w) << 16);
    val.z = f2bf(c1.x) | (f2bf(c1.y) << 16);
    val.w = f2bf(c1.z) | (f2bf(c1.w) << 16);
    *(uint4*)(BtT + (size_t)o * KKTOT + (size_t)i * NB) = val;
}

// 32x128 tile, 4 waves (each 32 rows x 32 cols), mfma_f32_16x16x32_bf16.
// A generated into double-buffered LDS (1 pack/thread/iter, one barrier/iter);
// B register-prefetched one iter ahead from L2-resident BtT.
__global__ __launch_bounds__(256, 4)
void kan_gemm(const float* __restrict__ X, const unsigned short* __restrict__ BtT,
              float* __restrict__ Out) {
    __shared__ unsigned short As[2][BM * LDK];   // 2 x 4.5 KB

    const int tid    = threadIdx.x;
    const int lane   = tid & 63;
    const int wv     = tid >> 6;     // 0..3: column group
    const int lane16 = lane & 15;
    const int quad   = lane >> 4;

    const int row0 = blockIdx.y * BM;
    const int col0 = blockIdx.x * BN;
    const int C0   = wv * 32;

    f32x4 acc[2][2] = {};            // [rm][cn]

    // A-gen: 256 (b,i) packs per tile, 1 per thread
    const int gb   = tid >> 3;       // 0..31 row in tile
    const int iloc = tid & 7;        // 0..7
    const float* xcol = X + (size_t)(row0 + gb) * IN_F + iloc;

    // B fragment base: col n = col0+C0+cn*16+lane16, k offset quad*8
    const unsigned short* bbase =
        BtT + (size_t)(col0 + C0 + lane16) * KKTOT + quad * 8;

    // prologue: A tile 0 into buffer 0; B frags for iter 0; x for iter 1
    {
        uint4 a0 = bspline_pack(xcol[0]);
        *(uint4*)&As[0][gb * LDK + iloc * NB] = a0;
    }
    s16x8 bc00 = *(const s16x8*)(bbase);                            // cn0 ks0
    s16x8 bc01 = *(const s16x8*)(bbase + 32);                       // cn0 ks1
    s16x8 bc10 = *(const s16x8*)(bbase + (size_t)16 * KKTOT);       // cn1 ks0
    s16x8 bc11 = *(const s16x8*)(bbase + (size_t)16 * KKTOT + 32);  // cn1 ks1
    float xnext = xcol[NB];
    __syncthreads();

    for (int it = 0; it < NITER; ++it) {
        const int cur = it & 1;

        // issue B prefetch for it+1 FIRST; sched_barrier pins the issue point
        // (R4 lesson: without it the scheduler sinks loads to their uses)
        s16x8 bn00, bn01, bn10, bn11;
        if (it + 1 < NITER) {
            const int kn = (it + 1) * BK;
            bn00 = *(const s16x8*)(bbase + kn);
            bn01 = *(const s16x8*)(bbase + kn + 32);
            bn10 = *(const s16x8*)(bbase + (size_t)16 * KKTOT + kn);
            bn11 = *(const s16x8*)(bbase + (size_t)16 * KKTOT + kn + 32);
        }
        __builtin_amdgcn_sched_barrier(0);

        // generate NEXT A tile into the other buffer (readers finished at
        // the barrier that ended iter it-1)
        if (it + 1 < NITER) {
            uint4 a0 = bspline_pack(xnext);
            *(uint4*)&As[cur ^ 1][gb * LDK + iloc * NB] = a0;
            if (it + 2 < NITER) xnext = xcol[(it + 2) * NB];
        }

        // compute on current buffer with current B frags (loaded last iter,
        // long since landed -> no vmcnt(0) drain on the critical path)
        #pragma unroll
        for (int ks = 0; ks < 2; ++ks) {
            const int koff = ks * 32 + quad * 8;
            s16x8 af0 = *(const s16x8*)&As[cur][(lane16) * LDK + koff];
            s16x8 af1 = *(const s16x8*)&As[cur][(16 + lane16) * LDK + koff];
            s16x8 b0 = ks ? bc01 : bc00;
            s16x8 b1 = ks ? bc11 : bc10;
            acc[0][0] = __builtin_amdgcn_mfma_f32_16x16x32_bf16(af0, b0, acc[0][0], 0, 0, 0);
            acc[1][0] = __builtin_amdgcn_mfma_f32_16x16x32_bf16(af1, b0, acc[1][0], 0, 0, 0);
            acc[0][1] = __builtin_amdgcn_mfma_f32_16x16x32_bf16(af0, b1, acc[0][1], 0, 0, 0);
            acc[1][1] = __builtin_amdgcn_mfma_f32_16x16x32_bf16(af1, b1, acc[1][1], 0, 0, 0);
        }
        __syncthreads();   // next-buffer A writes visible; current reads done

        if (it + 1 < NITER) { bc00 = bn00; bc01 = bn01; bc10 = bn10; bc11 = bn11; }
    }

    // Epilogue: C/D layout col=lane&15, row=quad*4+reg
    #pragma unroll
    for (int rm = 0; rm < 2; ++rm) {
        const int grow = row0 + rm * 16 + quad * 4;
        #pragma unroll
        for (int cn = 0; cn < 2; ++cn) {
            float* dst = Out + (size_t)grow * OUT_F + col0 + C0 + cn * 16 + lane16;
            #pragma unroll
            for (int r = 0; r < 4; ++r)
                dst[(size_t)r * OUT_F] = acc[rm][cn][r];
        }
    }
}

extern "C" void kernel_launch(void* const* d_in, const int* in_sizes, int n_in,
                              void* d_out, int out_size, void* d_ws, size_t ws_size,
                              hipStream_t stream) {
    const float* X  = (const float*)d_in[0];   // (8192, 512) f32
    const float* C  = (const float*)d_in[1];   // (512, 512, 8) f32
    // d_in[2] = grid (uniform; constants hardcoded)
    float* Out = (float*)d_out;                // (8192, 512) f32
    unsigned short* BtT = (unsigned short*)d_ws;  // 4 MB bf16 [o][i*8+k]

    prep_bt<<<dim3((IN_F * OUT_F) / 256), 256, 0, stream>>>(C, BtT);
    kan_gemm<<<dim3(OUT_F / BN, BATCH / BM), 256, 0, stream>>>(X, BtT, Out);
}

// Round 6
// 140.780 us; speedup vs baseline: 2.3392x; 1.3990x over previous
//
#include <hip/hip_runtime.h>
#include <hip/hip_bf16.h>
#include <stdint.h>

// BSpline KAN layer: out[b,o] = sum_{i,k} bases(tanh(x[b,i]))[k] * C[i,o,k]
// == GEMM M=8192, N=512, K=4096 with generated A. bf16 MFMA path.
// History:
//  R2  84us: A-in-LDS dbuf + per-wave B reg loads + __syncthreads. MfmaUtil 16.
//  R3/R7 REGRESSED: launch_bounds min-waves squeezed VGPR (32/40), killed
//      B pipelining. Lesson: never request occupancy the reg-plan can't afford.
//  R4 268us: per-wave PRIVATE full-width B = 4x TA traffic + load sinking.
//  Diagnosis of R2's 47% idle: __syncthreads forces s_waitcnt vmcnt(0)
//      (m97-documented) -> the B prefetch drains EVERY iter; plus A
//      pack->LDS->read roundtrip. MFMA pipe floor is 16.6us (19.4cyc/mfma).
//  R8: A = register-direct pack (R4 identity: A-frag lane=row lane16,
//      k=quad*8+j IS one bspline_pack of x[row][it*8+ks*4+quad]).
//      B = LDS via global_load_lds, 4 bufs, 2 tiles in flight, raw s_barrier
//      + counted asm vmcnt(6) (T3/T4) -> loads live across barriers.
//      B LDS chunk-swizzle j^=c&7 (both-sides involution) -> 2-way conflicts.

typedef short s16x8 __attribute__((ext_vector_type(8)));   // 8 bf16
typedef float f32x4 __attribute__((ext_vector_type(4)));

#define BATCH 8192
#define IN_F  512
#define OUT_F 512
#define NB    8            // GRID_SIZE + SPLINE_ORDER
#define KKTOT (IN_F * NB)  // 4096
#define BM 64
#define BN 128
#define BK 64              // 8 i's per K-tile; tile = 128 cols x 128 B
#define NITER (IN_F / NB)  // 64

__device__ __forceinline__ uint32_t f2bf(float f) {
    union { float f; uint32_t u; } v; v.f = f;
    return (v.u + 0x7FFFu + ((v.u >> 16) & 1u)) >> 16;   // RNE bf16
}

__device__ __forceinline__ uint32_t bf16bits(float a) {
    __hip_bfloat16 h = __float2bfloat16(a);               // RNE; compiler pairs
    union { __hip_bfloat16 h; unsigned short u; } c; c.h = h;
    return (uint32_t)c.u;
}

__device__ __forceinline__ s16x8 u4_to_s8(uint4 v) {
    union { uint4 u; s16x8 s; } c; c.u = v; return c.s;
}

// 8 basis values for one x, packed bf16 into 16 bytes (4 nonzero cubic
// B-spline weights shifted to slot j-3; uniform grid h=0.4, g0=-2.2).
__device__ __forceinline__ uint4 bspline_pack(float xraw) {
    float e  = __expf(2.0f * xraw);
    float xn = 1.0f - 2.0f / (e + 1.0f);          // tanh; inf->1, 0->-1
    float u  = __fmaf_rn(xn, 2.5f, 5.5f);         // (xn + 2.2) / 0.4
    float fj = floorf(u);
    fj = fminf(fmaxf(fj, 3.0f), 7.0f);            // cell j in [3,7]
    float t  = u - fj;                            // local coord in [0,1]
    float omt = 1.0f - t;
    float t2 = t * t;
    float t3 = t2 * t;
    const float s = 0.16666666666666666f;
    float w0 = s * omt * omt * omt;
    float w3 = s * t3;
    float w1 = s * __fmaf_rn(3.0f, t3, __fmaf_rn(-6.0f, t2, 4.0f));
    float w2 = 1.0f - w0 - w1 - w3;               // partition of unity
    uint64_t packed = (uint64_t)(bf16bits(w0) | (bf16bits(w1) << 16))
                    | ((uint64_t)(bf16bits(w2) | (bf16bits(w3) << 16)) << 32);
    int sh = ((int)fj - 3) * 16;                  // 0,16,32,48,64 bits
    uint64_t lo, hi;
    if (sh == 0)      { lo = packed;       hi = 0ull; }
    else if (sh < 64) { lo = packed << sh; hi = packed >> (64 - sh); }
    else              { lo = 0ull;         hi = packed; }
    return make_uint4((uint32_t)lo, (uint32_t)(lo >> 32),
                      (uint32_t)hi, (uint32_t)(hi >> 32));
}

// C[i][o][k] fp32 -> BtT[o][i*8+k] bf16. o-fastest: coalesced reads,
// scattered 16B stores (fire-and-forget, write-combined). Verified R0-R7.
__global__ __launch_bounds__(256)
void prep_bt(const float* __restrict__ C, unsigned short* __restrict__ BtT) {
    int t = blockIdx.x * 256 + threadIdx.x;
    int o = t & (OUT_F - 1);
    int i = t >> 9;
    const float4* src = (const float4*)(C + ((size_t)i * OUT_F + o) * NB);
    float4 c0 = src[0];
    float4 c1 = src[1];
    uint4 val;
    val.x = f2bf(c0.x) | (f2bf(c0.y) << 16);
    val.y = f2bf(c0.z) | (f2bf(c0.w) << 16);
    val.z = f2bf(c1.x) | (f2bf(c1.y) << 16);
    val.w = f2bf(c1.z) | (f2bf(c1.w) << 16);
    *(uint4*)(BtT + (size_t)o * KKTOT + (size_t)i * NB) = val;
}

__device__ __forceinline__ void gload_lds16(const void* g, void* l) {
    __builtin_amdgcn_global_load_lds(
        (const __attribute__((address_space(1))) uint32_t*)g,
        (__attribute__((address_space(3))) uint32_t*)l, 16, 0, 0);
}

// 64x128 tile, 4 waves (each 16 rows x 128 cols). A frags packed per-lane in
// registers; B tiles (128 cols x 128 B) staged to LDS, 4 buffers, counted
// vmcnt(6) so 2 stage batches stay in flight across raw s_barriers.
__global__ __launch_bounds__(256, 2)
void kan_gemm(const float* __restrict__ X, const unsigned short* __restrict__ BtT,
              float* __restrict__ Out) {
    // Bs[buf][c*128 + j*16 .. +15] holds global k-chunk (j ^ (c&7)) of col c.
    __shared__ unsigned short Bs[4][8192];   // 4 x 16 KB

    const int tid    = threadIdx.x;
    const int lane   = tid & 63;
    const int wv     = tid >> 6;     // 0..3: 16-row slice
    const int lane16 = lane & 15;
    const int quad   = lane >> 4;

    const int row0 = blockIdx.y * BM;
    const int col0 = blockIdx.x * BN;

    const float* xrow = X + (size_t)(row0 + wv * 16 + lane16) * IN_F;

    // ---- B stage addressing (pre-swizzled global source, rule #21) ----
    // wave w, round r: lane stages 16 B of col c = r*32 + w*8 + (lane>>3),
    // global chunk jg = (lane&7) ^ ((lane>>3)&7), LDS dest linear lane*16.
    const int jg = (lane & 7) ^ ((lane >> 3) & 7);
    const char* gstage = (const char*)BtT
        + ((size_t)(col0 + wv * 8 + (lane >> 3))) * (KKTOT * 2)
        + (size_t)jg * 16;

    // ---- B fragment read addressing (swizzled ds_read) ----
    // frag(cn,ks): col c = cn*16+lane16, chunk (ks*4+quad) ^ (lane16&7)
    const int cbyte = lane16 * 128;
    const int sx0 = ((quad)     ^ (lane16 & 7)) << 4;
    const int sx1 = ((4 + quad) ^ (lane16 & 7)) << 4;

    f32x4 acc[8] = {};
    float xs0a, xs0b, xs1a, xs1b, xs2a, xs2b, xs3a, xs3b;  // x slot per t&3

#define STAGE(BUF, T)                                                         \
    do {                                                                      \
        _Pragma("unroll")                                                     \
        for (int r = 0; r < 4; ++r)                                           \
            gload_lds16(gstage + (size_t)r * 32 * (KKTOT * 2) + (size_t)(T) * 128, \
                        (char*)&Bs[BUF][0] + r * 4096 + wv * 1024);           \
    } while (0)

    // prologue: tiles 0,1 + x(0),x(1) in flight; wait batch 0 only
    STAGE(0, 0);
    xs0a = xrow[quad];  xs0b = xrow[4 + quad];
    STAGE(1, 1);
    xs1a = xrow[8 + quad];  xs1b = xrow[12 + quad];
    asm volatile("s_waitcnt vmcnt(6)" ::: "memory");
    __builtin_amdgcn_s_barrier();

#define BODY(T, CUR, PRE, XCA, XCB, XPA, XPB)                                 \
    do {                                                                      \
        if ((T) + 2 < NITER) {                                                \
            STAGE(PRE, (T) + 2);                                              \
            XPA = xrow[((T) + 2) * 8 + quad];                                 \
            XPB = xrow[((T) + 2) * 8 + 4 + quad];                             \
        }                                                                     \
        const char* bsC = (const char*)&Bs[CUR][0];                           \
        {                                                                     \
            s16x8 af0 = u4_to_s8(bspline_pack(XCA));                          \
            _Pragma("unroll")                                                 \
            for (int cn = 0; cn < 8; ++cn) {                                  \
                s16x8 b = *(const s16x8*)(bsC + cn * 2048 + cbyte + sx0);     \
                acc[cn] = __builtin_amdgcn_mfma_f32_16x16x32_bf16(            \
                    af0, b, acc[cn], 0, 0, 0);                                \
            }                                                                 \
        }                                                                     \
        {                                                                     \
            s16x8 af1 = u4_to_s8(bspline_pack(XCB));                          \
            _Pragma("unroll")                                                 \
            for (int cn = 0; cn < 8; ++cn) {                                  \
                s16x8 b = *(const s16x8*)(bsC + cn * 2048 + cbyte + sx1);     \
                acc[cn] = __builtin_amdgcn_mfma_f32_16x16x32_bf16(            \
                    af1, b, acc[cn], 0, 0, 0);                                \
            }                                                                 \
        }                                                                     \
        if ((T) + 2 < NITER)                                                  \
            asm volatile("s_waitcnt vmcnt(6)" ::: "memory");                  \
        else if ((T) + 1 < NITER)                                             \
            asm volatile("s_waitcnt vmcnt(0)" ::: "memory");                  \
        if ((T) + 1 < NITER) __builtin_amdgcn_s_barrier();                    \
    } while (0)

    for (int t = 0; t < NITER; t += 4) {
        BODY(t + 0, 0, 2, xs0a, xs0b, xs2a, xs2b);
        BODY(t + 1, 1, 3, xs1a, xs1b, xs3a, xs3b);
        BODY(t + 2, 2, 0, xs2a, xs2b, xs0a, xs0b);
        BODY(t + 3, 3, 1, xs3a, xs3b, xs1a, xs1b);
    }
#undef BODY
#undef STAGE

    // Epilogue: C/D layout col=lane&15, row=quad*4+reg (verified R4)
    const int orow = row0 + wv * 16 + quad * 4;
    #pragma unroll
    for (int cn = 0; cn < 8; ++cn) {
        float* dst = Out + (size_t)orow * OUT_F + col0 + cn * 16 + lane16;
        #pragma unroll
        for (int r = 0; r < 4; ++r)
            dst[(size_t)r * OUT_F] = acc[cn][r];
    }
}

extern "C" void kernel_launch(void* const* d_in, const int* in_sizes, int n_in,
                              void* d_out, int out_size, void* d_ws, size_t ws_size,
                              hipStream_t stream) {
    const float* X  = (const float*)d_in[0];   // (8192, 512) f32
    const float* C  = (const float*)d_in[1];   // (512, 512, 8) f32
    // d_in[2] = grid (uniform; constants hardcoded)
    float* Out = (float*)d_out;                // (8192, 512) f32
    unsigned short* BtT = (unsigned short*)d_ws;  // 4 MB bf16 [o][i*8+k]

    prep_bt<<<dim3((IN_F * OUT_F) / 256), 256, 0, stream>>>(C, BtT);
    kan_gemm<<<dim3(OUT_F / BN, BATCH / BM), 256, 0, stream>>>(X, BtT, Out);
}